// Round 9
// baseline (80.689 us; speedup 1.0000x reference)
//
#include <hip/hip_runtime.h>
#include <float.h>

// ChamferLoss, single fused dispatch. B=4, N=16384, M=4096, fp32 in/out.
// loss[b] = (1/N) * sum_n min_m max(||p_bn - v_bm||^2, 0)
//
// d2 = pp + (v2 - 2 p.v). Bracket on the MATRIX pipe via split-bf16 packed
// into K=16 of mfma_f32_32x32x16_bf16 (validated R6-R8, absmax 0.0):
//   A row (point):  [ph x3, pl x3, ph x3, 1, 1, 0...]
//   B col (vert):   [-2vh x3, -2vh x3, -2vl x3, v2h, v2l, 0...]
//
// R9: ONE kernel. 512 blocks (2/CU), 4 waves, 1 point-tile (32 pts) per
// wave. Verts in 8 phases of 512: coalesced tv load -> register transform ->
// ds_write into 16KB double buffer (1 sync/phase) -> 16 MFMA+fmin tiles.
// Epilogue: shfl_xor butterfly col-min, +pp, clamp, block sum; cross-block
// finish via ws counter (CAS from 0xAA poison) - last block writes out.
// Removes: 2 extra dispatches + gaps, B-frag global round-trip, partial
// buffer, out-zeroing. Pipe budget/CU: LDS ~5.1us, VALU ~3.8us, MFMA ~0.9us.

typedef __bf16 bf16x8 __attribute__((ext_vector_type(8)));
typedef float  f32x16 __attribute__((ext_vector_type(16)));

constexpr int B = 4, N = 16384, M = 4096;
constexpr int TPB = 256;               // 4 waves
constexpr int PPB = 128;               // 32 points per wave
constexpr int NBLK = (B * N) / PPB;    // 512 blocks, 128 per batch
constexpr int PHASES = 8;
constexpr int PHASE_V = M / PHASES;    // 512 verts per phase
constexpr int PHASE_TILES = PHASE_V / 32;  // 16
constexpr unsigned POISON = 0xAAAAAAAAu;

__device__ __forceinline__ void write_vert(char* bp, int u,
                                           float x, float y, float z) {
    __bf16 xh = (__bf16)x, yh = (__bf16)y, zh = (__bf16)z;
    float xhf = (float)xh, yhf = (float)yh, zhf = (float)zh;
    __bf16 xl = (__bf16)(x - xhf), yl = (__bf16)(y - yhf), zl = (__bf16)(z - zhf);
    float v2 = fmaf(x, x, fmaf(y, y, z * z));
    __bf16 v2h = (__bf16)v2;
    __bf16 v2l = (__bf16)(v2 - (float)v2h);
    __bf16 zero = (__bf16)0.0f;
    bf16x8 h0, h1;
    h0[0] = (__bf16)(-2.0f * xhf); h0[1] = (__bf16)(-2.0f * yhf);
    h0[2] = (__bf16)(-2.0f * zhf);
    h0[3] = h0[0]; h0[4] = h0[1]; h0[5] = h0[2];
    h0[6] = (__bf16)(-2.0f * (float)xl); h0[7] = (__bf16)(-2.0f * (float)yl);
    h1[0] = (__bf16)(-2.0f * (float)zl); h1[1] = v2h; h1[2] = v2l;
    h1[3] = zero; h1[4] = zero; h1[5] = zero; h1[6] = zero; h1[7] = zero;
    char* base = bp + ((u >> 5) << 10) + ((u & 31) << 4);
    *(bf16x8*)base         = h0;
    *(bf16x8*)(base + 512) = h1;
}

__global__ __launch_bounds__(TPB, 2) void chamfer_fused(
    const float* __restrict__ src, const float* __restrict__ tv,
    float* __restrict__ out, float* __restrict__ ws)
{
    __shared__ char buf[2][PHASE_TILES * 1024];   // 2 x 16 KB
    __shared__ float acc[4];
    __shared__ int flag;

    const int blk  = blockIdx.x;
    const int b    = blk >> 7;             // 128 blocks per batch
    const int t    = threadIdx.x;
    const int w    = t >> 6, L = t & 63;
    const int half = L >> 5, c = L & 31;

    // ---- A-frag: this wave's 32 points (layout validated R6-R8). ----
    const int gp = blk * PPB + w * 32 + c;     // global point index
    float ax = src[3 * gp], ay = src[3 * gp + 1], az = src[3 * gp + 2];
    float pp = fmaf(ax, ax, fmaf(ay, ay, az * az));
    __bf16 one = (__bf16)1.0f, zero = (__bf16)0.0f;
    bf16x8 aA;
    {
        __bf16 xh = (__bf16)ax, yh = (__bf16)ay, zh = (__bf16)az;
        __bf16 xl = (__bf16)(ax - (float)xh), yl = (__bf16)(ay - (float)yh),
               zl = (__bf16)(az - (float)zh);
        if (half == 0) { aA[0]=xh; aA[1]=yh; aA[2]=zh; aA[3]=xl; aA[4]=yl; aA[5]=zl; aA[6]=xh; aA[7]=yh; }
        else { aA[0]=zh; aA[1]=one; aA[2]=one; aA[3]=zero; aA[4]=zero; aA[5]=zero; aA[6]=zero; aA[7]=zero; }
    }

    f32x16 mn, zeroC;
#pragma unroll
    for (int r = 0; r < 16; ++r) { mn[r] = FLT_MAX; zeroC[r] = 0.0f; }

    // ---- Vert pipeline: 8 phases x 512 verts, 2 verts/thread/phase. ----
    const float* tvb = tv + (size_t)b * M * 3;
    float r0, r1, r2, r3, r4, r5;
    {
        const float* p = tvb + 6 * t;
        float2 A = *(const float2*)p, Bq = *(const float2*)(p + 2),
               Cq = *(const float2*)(p + 4);
        r0 = A.x; r1 = A.y; r2 = Bq.x; r3 = Bq.y; r4 = Cq.x; r5 = Cq.y;
    }

    for (int phase = 0; phase < PHASES; ++phase) {
        char* bp = buf[phase & 1];
        write_vert(bp, 2 * t,     r0, r1, r2);
        write_vert(bp, 2 * t + 1, r3, r4, r5);
        if (phase + 1 < PHASES) {
            const float* p = tvb + (size_t)(phase + 1) * PHASE_V * 3 + 6 * t;
            float2 A = *(const float2*)p, Bq = *(const float2*)(p + 2),
                   Cq = *(const float2*)(p + 4);
            r0 = A.x; r1 = A.y; r2 = Bq.x; r3 = Bq.y; r4 = Cq.x; r5 = Cq.y;
        }
        __syncthreads();   // writes done; prior-phase consumers of this buf
                           // finished before their own writes above.
        const char* rp = bp + half * 512 + c * 16;
#pragma unroll 4
        for (int tl = 0; tl < PHASE_TILES; ++tl) {
            bf16x8 bf = *(const bf16x8*)(rp + tl * 1024);
            f32x16 C = __builtin_amdgcn_mfma_f32_32x32x16_bf16(aA, bf, zeroC, 0, 0, 0);
#pragma unroll
            for (int r = 0; r < 16; ++r) mn[r] = fminf(mn[r], C[r]);
        }
    }

    // ---- Epilogue: butterfly min across the 32 vert-columns. ----
#pragma unroll
    for (int off = 16; off > 0; off >>= 1) {
#pragma unroll
        for (int r = 0; r < 16; ++r)
            mn[r] = fminf(mn[r], __shfl_xor(mn[r], off, 64));
    }
    // C/D row = (r&3)+8*(r>>2)+4*half; lane c==row holds point (base+c),
    // whose pp this lane already computed. Select, add pp, clamp.
    float s = 0.0f;
#pragma unroll
    for (int r = 0; r < 16; ++r) {
        int row = (r & 3) + 8 * (r >> 2) + 4 * half;
        if (c == row) s = fmaxf(mn[r] + pp, 0.0f);
    }
    for (int off = 32; off > 0; off >>= 1)
        s += __shfl_down(s, off, 64);
    if (L == 0) acc[w] = s;
    __syncthreads();

    // ---- Cross-block finish (R3-validated counter protocol). ----
    if (t == 0) {
        float bs = acc[0] + acc[1] + acc[2] + acc[3];
        unsigned* cnt = (unsigned*)(ws + NBLK);
        atomicExch(&ws[blk], bs);
        __threadfence();
        (void)atomicCAS(cnt, POISON, 0u);   // first arrival zeroes poison
        __threadfence();
        unsigned n = atomicAdd(cnt, 1u);
        flag = (n == NBLK - 1) ? 1 : 0;
    }
    __syncthreads();

    if (flag) {   // last block: wave w sums batch w's 128 block-sums
        float s2 = atomicAdd(&ws[w * 128 + L], 0.0f)
                 + atomicAdd(&ws[w * 128 + 64 + L], 0.0f);
        for (int off = 32; off > 0; off >>= 1)
            s2 += __shfl_down(s2, off, 64);
        if (L == 0) out[w] = s2 * (1.0f / N);
    }
}

extern "C" void kernel_launch(void* const* d_in, const int* in_sizes, int n_in,
                              void* d_out, int out_size, void* d_ws, size_t ws_size,
                              hipStream_t stream) {
    const float* src = (const float*)d_in[0];    // (B, N, 3) fp32
    const float* tv  = (const float*)d_in[1];    // (B, M, 3) fp32
    float* out = (float*)d_out;                  // (B,) fp32
    float* ws  = (float*)d_ws;                   // 512 sums + counter

    chamfer_fused<<<NBLK, TPB, 0, stream>>>(src, tv, out, ws);
}

// Round 10
// 74.180 us; speedup vs baseline: 1.0877x; 1.0877x over previous
//
#include <hip/hip_runtime.h>
#include <float.h>

// ChamferLoss via MFMA, verts-as-rows: B=4, N=16384, M=4096, fp32 in/out.
// loss[b] = (1/N) * sum_n min_m max(||p_bn - v_bm||^2, 0)
//
// d2 = pp + (v2 - 2 p.v). Bracket on the MATRIX pipe via split-bf16 in K=16
// of mfma_f32_32x32x16_bf16 (encoding validated R6-R9, absmax 0.0):
//   A row (VERT):   [-2vh x3, -2vh x3, -2vl x3, v2h, v2l, 0...]
//   B col (POINT):  [ph x3, pl x3, ph x3, 1, 1, 0...]
//
// R10 key change: VERTS are now the MFMA rows, POINTS the cols. A lane's 16
// C-regs are then 16 verts of ONE point (C/D col = lane&31), so the min can
// fold ACROSS regs (v_min3_f32: 8 instrs/tile = 0.5 VALU lane-ops per pair,
// 4x less than points-as-rows where each reg was a different point). The
// cross-lane epilogue shrinks to one shfl_xor(32) (lane L and L+32 share a
// point) -- no LDS transpose. Fragment lane-mappings (row/col = lane&31,
// k-half = lane>>5) identical to the R6-validated ones.

typedef __bf16 bf16x8 __attribute__((ext_vector_type(8)));
typedef float  f32x16 __attribute__((ext_vector_type(16)));

constexpr int B = 4, N = 16384, M = 4096;
constexpr int BN = B * N;
constexpr int NCHUNK = 8;
constexpr int CHUNK_V = M / NCHUNK;          // 512 verts per chunk
constexpr int TILES = CHUNK_V / 32;          // 16 vert tiles per chunk
constexpr int TPB = 256;                     // 4 waves x 32 points
constexpr int PPB = 128;                     // points per block
constexpr int PBLK = BN / PPB;               // 512 point-blocks
constexpr size_t BFRAG_BYTES = (size_t)B * M * 32;   // 512 KB in ws

// ---- Pre-pass: per-vert A-frag K-vectors; zero out[]. ----
// Vert m of batch b -> byte offset:
//   b*131072 + chunk*16384 + tile*1024 + khalf*512 + row*16
__global__ __launch_bounds__(256) void chamfer_pre(
    const float* __restrict__ tv, unsigned char* __restrict__ bfr,
    float* __restrict__ out)
{
    if (blockIdx.x == 0 && threadIdx.x < B) out[threadIdx.x] = 0.0f;
    int i = blockIdx.x * 256 + threadIdx.x;      // 0..B*M-1
    int m = i & (M - 1);
    float x = tv[3 * i + 0], y = tv[3 * i + 1], z = tv[3 * i + 2];
    __bf16 xh = (__bf16)x, yh = (__bf16)y, zh = (__bf16)z;
    float xhf = (float)xh, yhf = (float)yh, zhf = (float)zh;
    __bf16 xl = (__bf16)(x - xhf), yl = (__bf16)(y - yhf), zl = (__bf16)(z - zhf);
    float v2 = fmaf(x, x, fmaf(y, y, z * z));
    __bf16 v2h = (__bf16)v2;
    __bf16 v2l = (__bf16)(v2 - (float)v2h);
    __bf16 zero = (__bf16)0.0f;

    bf16x8 h0, h1;
    h0[0] = (__bf16)(-2.0f * xhf); h0[1] = (__bf16)(-2.0f * yhf);
    h0[2] = (__bf16)(-2.0f * zhf);
    h0[3] = h0[0]; h0[4] = h0[1]; h0[5] = h0[2];
    h0[6] = (__bf16)(-2.0f * (float)xl); h0[7] = (__bf16)(-2.0f * (float)yl);
    h1[0] = (__bf16)(-2.0f * (float)zl); h1[1] = v2h; h1[2] = v2l;
    h1[3] = zero; h1[4] = zero; h1[5] = zero; h1[6] = zero; h1[7] = zero;

    int chunk = m >> 9, local = m & (CHUNK_V - 1), tile = local >> 5, r = m & 31;
    size_t base = (size_t)(i >> 12) * 131072 + (size_t)chunk * 16384
                + tile * 1024 + r * 16;
    *(bf16x8*)(bfr + base)       = h0;
    *(bf16x8*)(bfr + base + 512) = h1;
}

// ---- Main: 4096 blocks = 512 point-blocks x 8 chunks. ----
// Wave w: 32 points (cols) vs the block's 512-vert chunk (16 tiles).
// partial[chunk][point] = pp + min over chunk verts of (v2 - 2 p.v).
__global__ __launch_bounds__(TPB) void chamfer_mfma(
    const float* __restrict__ src, const unsigned char* __restrict__ bfr,
    float* __restrict__ partial)
{
    __shared__ uint4 lds4[1024];                 // 16 KB vert A-frags
    const char* ldsc = (const char*)lds4;
    const int blk   = blockIdx.x;
    const int chunk = blk & 7;
    const int pblk  = blk >> 3;                  // 0..511
    const int b     = pblk >> 7;                 // 128 point-blocks per batch
    const int t     = threadIdx.x;
    const int w     = t >> 6, L = t & 63;
    const int half  = L >> 5, c = L & 31;

    // Stage this chunk's 16 KB of vert A-frags (coalesced identity copy).
    const uint4* gsrc = (const uint4*)(bfr + (size_t)b * 131072 + (size_t)chunk * 16384);
#pragma unroll
    for (int i = 0; i < 4; ++i) lds4[i * 256 + t] = gsrc[i * 256 + t];

    // B-frag: this lane's point (col = c), split-bf16 encoding (R6-style).
    const int gp = pblk * PPB + w * 32 + c;
    float ax = src[3 * gp], ay = src[3 * gp + 1], az = src[3 * gp + 2];
    float pp = fmaf(ax, ax, fmaf(ay, ay, az * az));
    __bf16 one = (__bf16)1.0f, zero = (__bf16)0.0f;
    bf16x8 bP;
    {
        __bf16 xh = (__bf16)ax, yh = (__bf16)ay, zh = (__bf16)az;
        __bf16 xl = (__bf16)(ax - (float)xh), yl = (__bf16)(ay - (float)yh),
               zl = (__bf16)(az - (float)zh);
        if (half == 0) { bP[0]=xh; bP[1]=yh; bP[2]=zh; bP[3]=xl; bP[4]=yl; bP[5]=zl; bP[6]=xh; bP[7]=yh; }
        else { bP[0]=zh; bP[1]=one; bP[2]=one; bP[3]=zero; bP[4]=zero; bP[5]=zero; bP[6]=zero; bP[7]=zero; }
    }

    float mn[8];
    f32x16 zeroC;
#pragma unroll
    for (int u = 0; u < 8; ++u) mn[u] = FLT_MAX;
#pragma unroll
    for (int r = 0; r < 16; ++r) zeroC[r] = 0.0f;

    __syncthreads();

    // Inner loop: 1 ds_read_b128 (vert frag) + 1 MFMA + 8 v_min3_f32.
    // C-reg r is vert-row (r&3)+8*(r>>2)+4*half of this tile, col = point c
    // -> folding across regs is a legal vert-min.
    const int laneoff = half * 512 + c * 16;
#pragma unroll 4
    for (int tl = 0; tl < TILES; ++tl) {
        bf16x8 av = *(const bf16x8*)(ldsc + tl * 1024 + laneoff);
        f32x16 C = __builtin_amdgcn_mfma_f32_32x32x16_bf16(av, bP, zeroC, 0, 0, 0);
#pragma unroll
        for (int u = 0; u < 8; ++u)
            mn[u] = fminf(fminf(mn[u], C[2 * u]), C[2 * u + 1]);   // v_min3
    }

    // Epilogue: fold 8 accumulators in-lane, merge halves (L vs L+32 hold
    // the same point), add pp, coalesced store by half-0 lanes.
    float m01 = fminf(fminf(mn[0], mn[1]), fminf(mn[2], mn[3]));
    float m23 = fminf(fminf(mn[4], mn[5]), fminf(mn[6], mn[7]));
    float m = fminf(m01, m23);
    m = fminf(m, __shfl_xor(m, 32, 64));
    if (L < 32)
        partial[(size_t)chunk * BN + gp] = m + pp;
}

// ---- Reduce: min over 8 chunks, clamp, per-batch mean. ----
__global__ __launch_bounds__(256) void chamfer_reduce(
    const float* __restrict__ partial, float* __restrict__ out)
{
    const int p = blockIdx.x * 256 + threadIdx.x;
    const int b = blockIdx.x >> 6;               // 64 blocks per batch
    float m = FLT_MAX;
#pragma unroll
    for (int cgr = 0; cgr < NCHUNK; ++cgr)
        m = fminf(m, partial[(size_t)cgr * BN + p]);
    float sum = fmaxf(m, 0.0f);

    for (int off = 32; off > 0; off >>= 1)
        sum += __shfl_down(sum, off, 64);
    __shared__ float acc[4];
    if ((threadIdx.x & 63) == 0) acc[threadIdx.x >> 6] = sum;
    __syncthreads();
    if (threadIdx.x == 0) {
        float s = acc[0] + acc[1] + acc[2] + acc[3];
        atomicAdd(&out[b], s * (1.0f / N));
    }
}

extern "C" void kernel_launch(void* const* d_in, const int* in_sizes, int n_in,
                              void* d_out, int out_size, void* d_ws, size_t ws_size,
                              hipStream_t stream) {
    const float* src = (const float*)d_in[0];    // (B, N, 3) fp32
    const float* tv  = (const float*)d_in[1];    // (B, M, 3) fp32
    float* out = (float*)d_out;                  // (B,) fp32
    unsigned char* bfr = (unsigned char*)d_ws;   // 512 KB vert A-frags
    float* partial = (float*)((char*)d_ws + BFRAG_BYTES);  // 2 MB

    chamfer_pre   <<<(B * M) / 256, 256, 0, stream>>>(tv, bfr, out);
    chamfer_mfma  <<<PBLK * NCHUNK, TPB, 0, stream>>>(src, bfr, partial);
    chamfer_reduce<<<BN / 256, 256, 0, stream>>>(partial, out);
}